// Round 8
// baseline (268.244 us; speedup 1.0000x reference)
//
#include <hip/hip_runtime.h>
#include <hip/hip_bf16.h>
#include <stdint.h>

#define B_TOT 4096
#define D_DIM 512
#define NKT 24

typedef __attribute__((ext_vector_type(4))) float f32x4;
typedef __attribute__((ext_vector_type(8))) short short8;

__device__ __forceinline__ float gumbelf(float u) {
  // fast gumbel: raw v_log_f32 (×ln2). Key perturbation ~1e-6, 100x below the
  // bf16-split dist noise (~2e-4) that already bounds argmax stability.
  return -__logf(-__logf(u + 1e-12f) + 1e-12f);
}

__device__ __forceinline__ unsigned short f2bf(float f) {
  unsigned int u = __float_as_uint(f);
  unsigned int r = u + 0x7fffu + ((u >> 16) & 1u);   // RNE to bf16
  return (unsigned short)(r >> 16);
}

__device__ __forceinline__ void gload_lds16(const void* g, void* l) {
  __builtin_amdgcn_global_load_lds(
      (const __attribute__((address_space(1))) void*)g,
      (__attribute__((address_space(3))) void*)l, 16, 0, 0);
}

// ------ kernel 1: fused bf16 split + sq + positive sampling (f32 exact) ------
__global__ __launch_bounds__(64) void prep_pos_kernel(
    const float* __restrict__ feat, const float* __restrict__ u_pos,
    unsigned short* __restrict__ FH, unsigned short* __restrict__ FL,
    float* __restrict__ sq, float* __restrict__ thresh,
    float* __restrict__ score_pos, float* __restrict__ score_pos1,
    int* __restrict__ counters) {
  const int i = blockIdx.x;
  const int lane = threadIdx.x;
  const int c0 = i & ~7;
  const float* xr = feat + (size_t)i * D_DIM + lane * 8;
  const float4 x0 = *(const float4*)xr;
  const float4 x1 = *(const float4*)(xr + 4);
  float v[8] = {x0.x, x0.y, x0.z, x0.w, x1.x, x1.y, x1.z, x1.w};

  short8 hv, lv;
#pragma unroll
  for (int k = 0; k < 8; ++k) {
    unsigned short h = f2bf(v[k]);
    float hf = __uint_as_float((unsigned int)h << 16);
    unsigned short l = f2bf(v[k] - hf);
    hv[k] = (short)h;
    lv[k] = (short)l;
  }
  const size_t off = (size_t)i * D_DIM + lane * 8;
  *(short8*)(FH + off) = hv;
  *(short8*)(FL + off) = lv;

  float p8[8], s8[8];
#pragma unroll
  for (int jj = 0; jj < 8; ++jj) {
    const float* yr = feat + (size_t)(c0 + jj) * D_DIM + lane * 8;
    const float4 y0 = *(const float4*)yr;
    const float4 y1 = *(const float4*)(yr + 4);
    float yv[8] = {y0.x, y0.y, y0.z, y0.w, y1.x, y1.y, y1.z, y1.w};
    float p = 0.f, s = 0.f;
#pragma unroll
    for (int k = 0; k < 8; ++k) { p += v[k] * yv[k]; s += yv[k] * yv[k]; }
#pragma unroll
    for (int m = 32; m >= 1; m >>= 1) {
      p += __shfl_xor(p, m);
      s += __shfl_xor(s, m);
    }
    p8[jj] = p; s8[jj] = s;
  }
  const float sqi = s8[i & 7];
  float dj[8];
#pragma unroll
  for (int jj = 0; jj < 8; ++jj)
    dj[jj] = fmaxf(sqi + s8[jj] - 2.f * p8[jj], 1e-8f);

  if (lane == 0) {
    sq[i] = sqi;
    float mx = 0.f, blg = -3e30f, bd = 0.f;
#pragma unroll
    for (int jj = 0; jj < 8; ++jj) {
      const int j = c0 + jj;
      if (j == i) continue;
      mx = fmaxf(mx, dj[jj]);
      const float lg = __logf(dj[jj] + 1e-30f) + gumbelf(u_pos[(size_t)i * B_TOT + j]);
      if (lg > blg) { blg = lg; bd = dj[jj]; }
    }
    thresh[i] = bd + 1e-4f;
    score_pos[i] = sqrtf(bd);
    score_pos1[i] = sqrtf(mx);
    if (i == 0) { counters[0] = 0; counters[1] = 0; counters[2] = 0; }
  }
}

// ------- kernel 2: split-bf16 GEMM (K=1536) + fused negative reduction -------
// 256x256 tile, 8 waves (2Mx4N), BK=64, double-buffered LDS, both-sides XOR
// swizzle, XCD-chunked block swizzle (T1), counted-vmcnt pipeline (T4),
// phase-split MFMA clusters with setprio (T5).
__global__ __launch_bounds__(512, 2) void neg_kernel(
    const unsigned short* __restrict__ FH, const unsigned short* __restrict__ FL,
    const float* __restrict__ u_neg, const float* __restrict__ sq,
    const float* __restrict__ thresh, float4* __restrict__ part) {
  __shared__ __align__(16) unsigned short As[2][256 * 64];
  __shared__ __align__(16) unsigned short Bs[2][256 * 64];
  const int tid = threadIdx.x;
  const int lane = tid & 63;
  const int w = tid >> 6;            // wave 0..7
  const int wm = w >> 2, wn = w & 3; // 2M x 4N wave grid
  const int b15 = lane & 15, q = lane >> 4;

  // T1: bijective XCD-chunked swizzle (256 blocks, 8 XCDs -> 4x8 rectangles)
  const int lid = blockIdx.y * 16 + blockIdx.x;
  const int xcd = lid & 7, rr = lid >> 3;          // rr: 0..31
  const int bx = (xcd & 3) * 4 + (rr & 3);
  const int by = (xcd >> 2) * 8 + (rr >> 2);
  const int i0 = bx * 256, jt = by * 256;

  f32x4 acc[8][4];
#pragma unroll
  for (int m = 0; m < 8; ++m)
#pragma unroll
    for (int n = 0; n < 4; ++n) acc[m][n] = (f32x4){0.f, 0.f, 0.f, 0.f};

  const int grow = tid >> 3;                       // 0..63: LDS row base this thread fills
  const int sslot = (tid & 7) ^ ((tid >> 3) & 7);  // pre-swizzled global 16B slot
  const int xorv = b15 & 7;                        // read-side XOR (same involution)

  auto STAGE = [&](int nb, int kt) {
    const int seg = kt >> 3;  // 0: h.h, 1: l.h, 2: h.l
    const unsigned short* Asrc = (seg == 1) ? FL : FH;
    const unsigned short* Bsrc = (seg == 2) ? FL : FH;
    const int kcol = (kt & 7) * 64 + sslot * 8;
#pragma unroll
    for (int r = 0; r < 4; ++r) {
      gload_lds16(Asrc + (size_t)(i0 + r * 64 + grow) * D_DIM + kcol,
                  (char*)As[nb] + r * 8192 + w * 1024);
      gload_lds16(Bsrc + (size_t)(jt + r * 64 + grow) * D_DIM + kcol,
                  (char*)Bs[nb] + r * 8192 + w * 1024);
    }
  };

  auto COMPUTE = [&](int cb) {
    short8 bfr[4][2];
#pragma unroll
    for (int nn = 0; nn < 4; ++nn)
#pragma unroll
      for (int ks = 0; ks < 2; ++ks)
        bfr[nn][ks] = *(const short8*)(&Bs[cb][(wn * 64 + nn * 16 + b15) * 64 +
                                               (((ks * 4 + q) ^ xorv) * 8)]);
#pragma unroll
    for (int h = 0; h < 2; ++h) {       // 2 MFMA clusters (row halves)
      short8 afr[4][2];
#pragma unroll
      for (int mm = 0; mm < 4; ++mm)
#pragma unroll
        for (int ks = 0; ks < 2; ++ks)
          afr[mm][ks] = *(const short8*)(&As[cb][(wm * 128 + (h * 4 + mm) * 16 + b15) * 64 +
                                                 (((ks * 4 + q) ^ xorv) * 8)]);
      __builtin_amdgcn_s_setprio(1);
#pragma unroll
      for (int mm = 0; mm < 4; ++mm)
#pragma unroll
        for (int nn = 0; nn < 4; ++nn)
#pragma unroll
          for (int ks = 0; ks < 2; ++ks)
            acc[h * 4 + mm][nn] = __builtin_amdgcn_mfma_f32_16x16x32_bf16(
                afr[mm][ks], bfr[nn][ks], acc[h * 4 + mm][nn], 0, 0, 0);
      __builtin_amdgcn_s_setprio(0);
    }
  };

  // T4 counted-vmcnt K-loop: 8 loads/STAGE; vmcnt(8) waits the tile issued
  // one full iteration earlier; prefetch stays in flight across barriers.
  STAGE(0, 0);
#pragma unroll 1
  for (int kt = 0; kt < NKT - 1; ++kt) {
    asm volatile("" ::: "memory");
    STAGE((kt & 1) ^ 1, kt + 1);         // outstanding: 8(kt) + 8(kt+1)
    asm volatile("s_waitcnt vmcnt(8)" ::: "memory");  // kt's 8 landed (mine)
    __builtin_amdgcn_s_barrier();        // everyone's kt landed
    COMPUTE(kt & 1);
    asm volatile("" ::: "memory");
    __builtin_amdgcn_s_barrier();        // all waves done reading buf kt&1
  }
  asm volatile("s_waitcnt vmcnt(0)" ::: "memory");   // last tile landed
  __builtin_amdgcn_s_barrier();

  // hoisted u_neg gather burst, half 0 (hidden under the final COMPUTE)
  float uval[4][4][4];
  auto BURST = [&](int h) {
#pragma unroll
    for (int mm = 0; mm < 4; ++mm)
#pragma unroll
      for (int r = 0; r < 4; ++r) {
        const size_t rowo = (size_t)(i0 + wm * 128 + (h * 4 + mm) * 16 + q * 4 + r) * B_TOT;
#pragma unroll
        for (int nn = 0; nn < 4; ++nn)
          uval[mm][r][nn] = u_neg[rowo + jt + wn * 64 + nn * 16 + b15];
      }
  };
  BURST(0);
  asm volatile("" ::: "memory");
  COMPUTE(1);                            // kt=23; As[0]/Bs[0] free afterwards

  // epilogue: dist + min + masked gumbel-argmax, butterfly per 16-lane group,
  // results written straight to LDS red table (reuses As[0])
  float4* red4 = (float4*)As[0];         // [256 rows][4 wn slots]
  auto EPI = [&](int h) {
#pragma unroll
    for (int mm = 0; mm < 4; ++mm) {
#pragma unroll
      for (int r = 0; r < 4; ++r) {
        const int mmg = h * 4 + mm;
        const int ro = wm * 128 + mmg * 16 + q * 4 + r;
        const int gi = i0 + ro;
        const float sqi = sq[gi];
        const float th = thresh[gi];
        const int cls = gi >> 3;
        float c_min = 3e38f, c_lg = -1e30f, c_d = 0.f;
        int c_ix = 0;
#pragma unroll
        for (int nn = 0; nn < 4; ++nn) {
          const int gj = jt + wn * 64 + nn * 16 + b15;
          if ((gj >> 3) != cls) {
            const float g = acc[mmg][nn][r];
            const float dist = fmaxf(sqi + sq[gj] - 2.f * g, 1e-8f);
            c_min = fminf(c_min, dist);
            if (dist < th) {
              const float lg = gumbelf(uval[mm][r][nn]) - dist;
              if (lg > c_lg || (lg == c_lg && gj < c_ix)) { c_lg = lg; c_d = dist; c_ix = gj; }
            }
          }
        }
#pragma unroll
        for (int s = 1; s < 16; s <<= 1) {
          const float omin = __shfl_xor(c_min, s);
          const float olg = __shfl_xor(c_lg, s);
          const float od = __shfl_xor(c_d, s);
          const int oix = __shfl_xor(c_ix, s);
          c_min = fminf(c_min, omin);
          if (olg > c_lg || (olg == c_lg && oix < c_ix)) { c_lg = olg; c_d = od; c_ix = oix; }
        }
        if (b15 == ((mmg * 4 + r) & 15))
          red4[ro * 4 + wn] = make_float4(c_min, c_lg, c_d, __int_as_float(c_ix));
      }
    }
  };
  EPI(0);
  BURST(1);
  EPI(1);

  __syncthreads();
  if (tid < 256) {
    const float4 s0 = red4[tid * 4 + 0];
    const float4 s1 = red4[tid * 4 + 1];
    const float4 s2 = red4[tid * 4 + 2];
    const float4 s3 = red4[tid * 4 + 3];
    float mn = fminf(fminf(s0.x, s1.x), fminf(s2.x, s3.x));
    float lg = s0.y, d = s0.z;
    int ix = __float_as_int(s0.w);
    if (s1.y > lg || (s1.y == lg && __float_as_int(s1.w) < ix)) { lg = s1.y; d = s1.z; ix = __float_as_int(s1.w); }
    if (s2.y > lg || (s2.y == lg && __float_as_int(s2.w) < ix)) { lg = s2.y; d = s2.z; ix = __float_as_int(s2.w); }
    if (s3.y > lg || (s3.y == lg && __float_as_int(s3.w) < ix)) { lg = s3.y; d = s3.z; ix = __float_as_int(s3.w); }
    part[(size_t)(i0 + tid) * 16 + by] = make_float4(mn, lg, d, __int_as_float(ix));
  }
}

// -------- kernel 3: per-row combine + loss + ticketed scalar finalize --------
__global__ __launch_bounds__(256) void fin_kernel(
    const float4* __restrict__ part, const float* __restrict__ feat,
    const float* __restrict__ sq, const float* __restrict__ score_pos,
    const float* __restrict__ score_pos1, float* __restrict__ out,
    int* __restrict__ counters) {
  const int i = blockIdx.x * 256 + threadIdx.x;
  float mn = 3e38f, lg = -2e30f, d = 0.f;
  int ix = 0;
#pragma unroll
  for (int s = 0; s < 16; ++s) {
    const float4 p = part[(size_t)i * 16 + s];
    mn = fminf(mn, p.x);
    if (p.y > lg) { lg = p.y; d = p.z; ix = __float_as_int(p.w); }
  }
  float negd;
  if (lg > -1e29f) {
    negd = d;
  } else {
    // fallback: reference picks column 0 (first dist_neg>0 is always j=0)
    if ((i >> 3) == 0) {
      negd = 1e25f;
    } else {
      float dot = 0.f;
      for (int k = 0; k < D_DIM; ++k) dot += feat[(size_t)i * D_DIM + k] * feat[k];
      negd = fmaxf(sq[i] + sq[0] - 2.f * dot, 1e-8f);
    }
  }
  const float sneg = sqrtf(negd);
  const float sneg1 = sqrtf(mn);
  const float diff = 1e-4f + score_pos[i] - sneg;
  out[i] = diff > 0.f ? diff + log1pf(expf(-diff)) : log1pf(expf(diff));
  const unsigned long long mact = __ballot(diff > 0.f);
  const unsigned long long macc = __ballot(score_pos1[i] < sneg1);
  if ((threadIdx.x & 63) == 0) {
    atomicAdd(counters + 0, (int)__popcll(mact));
    atomicAdd(counters + 1, (int)__popcll(macc));
  }
  // last-block-done ticket: scalar outputs fused into this dispatch
  __syncthreads();
  __threadfence();
  if (threadIdx.x == 0) {
    const int t = atomicAdd(counters + 2, 1);
    if (t == (int)gridDim.x - 1) {
      const int a = atomicAdd(counters + 0, 0);   // coherent read (bypass L1)
      const int c = atomicAdd(counters + 1, 0);
      out[B_TOT] = (float)a / (float)B_TOT;
      out[B_TOT + 1] = 100.f * (float)c / (float)B_TOT;
    }
  }
}

extern "C" void kernel_launch(void* const* d_in, const int* in_sizes, int n_in,
                              void* d_out, int out_size, void* d_ws, size_t ws_size,
                              hipStream_t stream) {
  const float* feat = (const float*)d_in[0];
  const float* u_pos = (const float*)d_in[1];
  const float* u_neg = (const float*)d_in[2];
  float* out = (float*)d_out;
  char* ws = (char*)d_ws;
  unsigned short* FH = (unsigned short*)(ws);                       // 4 MiB
  unsigned short* FL = (unsigned short*)(ws + 4194304);             // 4 MiB
  float* sq = (float*)(ws + 8388608);                               // 16 KB
  float* thresh = (float*)(ws + 8388608 + 16384);                   // 16 KB
  float* score_pos = (float*)(ws + 8388608 + 2 * 16384);            // 16 KB
  float* score_pos1 = (float*)(ws + 8388608 + 3 * 16384);           // 16 KB
  float4* part = (float4*)(ws + 8388608 + 4 * 16384);               // 1 MiB
  int* counters = (int*)(ws + 8388608 + 4 * 16384 + 2097152);

  prep_pos_kernel<<<B_TOT, 64, 0, stream>>>(feat, u_pos, FH, FL, sq, thresh,
                                            score_pos, score_pos1, counters);
  neg_kernel<<<dim3(16, 16), 512, 0, stream>>>(FH, FL, u_neg, sq, thresh, part);
  fin_kernel<<<16, 256, 0, stream>>>(part, feat, sq, score_pos, score_pos1, out, counters);
}